// Round 1
// baseline (343.581 us; speedup 1.0000x reference)
//
#include <hip/hip_runtime.h>
#include <math.h>

// Problem constants (from reference): B=64, S=4096, D=256
#define B_   64
#define S_   4096
#define D_   256
#define CH   32                          // chunks per batch (split-softmax partials)
#define ROWS_PER_CHUNK (S_ / CH)         // 128
#define NWAVE 4
#define RPW   8                          // rows per wave per iteration (8 lanes per row)
#define ROWS_PER_BLOCK_ITER (NWAVE * RPW)             // 32
#define NITER (ROWS_PER_CHUNK / ROWS_PER_BLOCK_ITER)  // 4
#define LN_EPS 1e-3f

typedef float f4 __attribute__((ext_vector_type(4)));

// Pass 1: one block per (batch, chunk).
// R5 change: 8 lanes per row (was 16), each lane owns 32 features (8x f4).
//  - butterfly reduce: 3 rounds (was 4), 1.125 shuffles/row (was 3)
//  - online-softmax iterations per wave: 4 (was 8) -> serial chain halved
//  - 8 KiB/wave prefetch in flight (was 4 KiB)
// Theory: 343 us @ ~0.78 TB/s (12% of achievable) with no throughput wall in
// sight (BW floor 43 us, VALU floor ~7 us) => exposed per-wave serial latency
// from the dependent shuffle butterfly + softmax chain. This halves that chain.
//
// NOTE (R3 lesson, kept): do NOT fuse the merge with per-block __threadfence() —
// agent-scope fences emit buffer_wbl2 (L2 writeback) per block; 2048 blocks
// serialize on L2 coherence traffic => 530 µs kernel at 3% HBM BW.
__global__ __launch_bounds__(256) void pool_pass1(
    const float* __restrict__ x, const float* __restrict__ mask,
    const float* __restrict__ gamma, const float* __restrict__ w,
    float* __restrict__ ws_acc, float* __restrict__ ws_m, float* __restrict__ ws_l)
{
    const int blk   = blockIdx.x;
    const int b     = blk / CH;
    const int chunk = blk % CH;
    const int tid   = threadIdx.x;
    const int lane  = tid & 63;
    const int wave  = tid >> 6;
    const int o     = lane >> 3;   // octet: which of 8 rows this lane works on
    const int t     = lane & 7;    // sublane within the row's 8-lane team

    // gamma*w for this lane's 32 features (beta & dense-bias cancel in softmax)
    f4 gw[8];
    float sgw = 0.0f;
    #pragma unroll
    for (int k = 0; k < 8; ++k) {
        const int d = t * 4 + 32 * k;
        const f4 g4 = *(const f4*)(gamma + d);
        const f4 w4 = *(const f4*)(w + d);
        gw[k] = g4 * w4;
        sgw += gw[k][0] + gw[k][1] + gw[k][2] + gw[k][3];
    }
    #pragma unroll
    for (int off = 4; off > 0; off >>= 1) sgw += __shfl_xor(sgw, off, 64);

    // this lane's row at iteration i: chunk*128 + i*32 + wave*8 + o
    const int row0 = chunk * ROWS_PER_CHUNK + wave * RPW + o;
    const float* xbase = x + ((size_t)b * S_ + row0) * D_ + t * 4;
    const float* mbase = mask + (size_t)b * S_ + row0;

    float m = -3.0e38f;
    float l = 0.0f;
    f4 acc[8];
    #pragma unroll
    for (int k = 0; k < 8; ++k) acc[k] = (f4)0.0f;

    // depth-1 prefetch: 8 KiB of row data in flight across the reduce/softmax.
    // x is read exactly once -> non-temporal (evict-first; no reuse to protect).
    f4 v[8];
    #pragma unroll
    for (int k = 0; k < 8; ++k)
        v[k] = __builtin_nontemporal_load((const f4*)(xbase + 32 * k));
    float msk = mbase[0];

    for (int i = 0; i < NITER; ++i) {
        const int inx = (i + 1 < NITER) ? i + 1 : i;
        f4 vn[8];
        #pragma unroll
        for (int k = 0; k < 8; ++k)
            vn[k] = __builtin_nontemporal_load(
                (const f4*)(xbase + (size_t)inx * ROWS_PER_BLOCK_ITER * D_ + 32 * k));
        const float mskn = mbase[inx * ROWS_PER_BLOCK_ITER];

        // three row reductions over the same data: sum, sumsq, dot(gamma*w)
        float s1 = 0.f, s2 = 0.f, s3 = 0.f;
        #pragma unroll
        for (int k = 0; k < 8; ++k) {
            #pragma unroll
            for (int j = 0; j < 4; ++j) {
                const float e = v[k][j];
                s1 += e;
                s2 += e * e;
                s3 += e * gw[k][j];
            }
        }
        // 3-round butterfly within the 8-lane team (s1,s2,s3 pipeline per round)
        #pragma unroll
        for (int off = 4; off > 0; off >>= 1) {
            s1 += __shfl_xor(s1, off, 64);
            s2 += __shfl_xor(s2, off, 64);
            s3 += __shfl_xor(s3, off, 64);
        }
        const float mu    = s1 * (1.0f / D_);
        const float var   = s2 * (1.0f / D_) - mu * mu;
        const float rstd  = rsqrtf(var + LN_EPS);
        const float score = rstd * (s3 - mu * sgw) + (1.0f - msk) * -1e9f;

        // online softmax update (identical within each 8-lane team)
        const float mnew  = fmaxf(m, score);
        const float scale = __expf(m - mnew);
        const float p     = __expf(score - mnew);
        m = mnew;
        l = l * scale + p;
        #pragma unroll
        for (int k = 0; k < 8; ++k) acc[k] = acc[k] * scale + p * v[k];

        #pragma unroll
        for (int k = 0; k < 8; ++k) v[k] = vn[k];
        msk = mskn;
    }

    // combine the 32 row-groups' partials in LDS
    __shared__ float s_acc[ROWS_PER_BLOCK_ITER][D_];  // 32 KiB
    __shared__ float s_m[ROWS_PER_BLOCK_ITER];
    __shared__ float s_l[ROWS_PER_BLOCK_ITER];
    const int g = wave * RPW + o;
    #pragma unroll
    for (int k = 0; k < 8; ++k) *(f4*)&s_acc[g][t * 4 + 32 * k] = acc[k];
    if (t == 0) { s_m[g] = m; s_l[g] = l; }
    __syncthreads();

    float M = -3.0e38f;
    #pragma unroll
    for (int gg = 0; gg < ROWS_PER_BLOCK_ITER; ++gg) M = fmaxf(M, s_m[gg]);
    float L = 0.f, a = 0.f;
    #pragma unroll
    for (int gg = 0; gg < ROWS_PER_BLOCK_ITER; ++gg) {
        const float e = __expf(s_m[gg] - M);
        L += e * s_l[gg];
        a += e * s_acc[gg][tid];
    }
    ws_acc[(size_t)blk * D_ + tid] = a;
    if (tid == 0) { ws_m[blk] = M; ws_l[blk] = L; }
}

// Pass 2: merge the CH partials per batch. One block per batch, one thread per d.
__global__ __launch_bounds__(256) void pool_pass2(
    const float* __restrict__ ws_acc, const float* __restrict__ ws_m,
    const float* __restrict__ ws_l, float* __restrict__ out)
{
    const int b = blockIdx.x;
    const int d = threadIdx.x;

    float M = -3.0e38f;
    #pragma unroll
    for (int c = 0; c < CH; ++c) M = fmaxf(M, ws_m[b * CH + c]);

    float L = 0.0f, a = 0.0f;
    #pragma unroll
    for (int c = 0; c < CH; ++c) {
        const float e = __expf(ws_m[b * CH + c] - M);
        L += e * ws_l[b * CH + c];
        a += e * ws_acc[((size_t)(b * CH + c)) * D_ + d];
    }
    out[(size_t)b * D_ + d] = a / L;
}

extern "C" void kernel_launch(void* const* d_in, const int* in_sizes, int n_in,
                              void* d_out, int out_size, void* d_ws, size_t ws_size,
                              hipStream_t stream) {
    // setup_inputs order: x, mask, gamma, beta, w, b
    const float* x     = (const float*)d_in[0];
    const float* mask  = (const float*)d_in[1];
    const float* gamma = (const float*)d_in[2];
    // d_in[3] = beta : cancels in softmax, unused
    const float* w     = (const float*)d_in[4];
    // d_in[5] = b    : cancels in softmax, unused
    float* out = (float*)d_out;

    // workspace layout: acc[B*CH*D] | m[B*CH] | l[B*CH]  (~2.02 MB)
    float* ws_acc = (float*)d_ws;
    float* ws_m   = ws_acc + (size_t)B_ * CH * D_;
    float* ws_l   = ws_m + B_ * CH;

    pool_pass1<<<B_ * CH, 256, 0, stream>>>(x, mask, gamma, w, ws_acc, ws_m, ws_l);
    pool_pass2<<<B_, 256, 0, stream>>>(ws_acc, ws_m, ws_l, out);
}